// Round 9
// baseline (77.784 us; speedup 1.0000x reference)
//
#include <hip/hip_runtime.h>
#include <hip/hip_bf16.h>
#include <math.h>

#define B_ 128
#define C_ 8
#define T_ 128
#define K_ 20
#define S_ 128

#define XROW 388            // cc x row stride: %4==0 (float4), %32==4 (groups de-alias)
#define BTROW 132
#define SWZ(j) ((j) ^ ((((j) >> 5) & 7) << 2))
#define XP_GUARD 16
#define BT_BASE (4 * XROW + XP_GUARD)   // 1568 floats
#define TILEF 1536          // [128][12]: x[t][c] cols 0-7, X2 col 8
#define SMEMF 3680          // max(dtw 2*1536=3072, cc 3680)

template <int CTRL, int RMASK>
__device__ __forceinline__ float dppf(float oldv, float v) {
    return __int_as_float(__builtin_amdgcn_update_dpp(
        __float_as_int(oldv), __float_as_int(v), CTRL, RMASK, 0xf, false));
}

// 1600 blocks x 256 threads. u%5==0 -> DTW (4 waves, TWO pairs per wave,
// row-sweep min-plus scan, two interleaved scan chains). Else -> CC (4 waves
// share one (b,half) x-tile; each wave one k: 4 ch x 16 lanes x 16 lags).
__global__ __launch_bounds__(256) void fused_kernel(const float* __restrict__ x,
                                                    const float* __restrict__ bary,
                                                    const float* __restrict__ top_dist,
                                                    const float* __restrict__ bottom_cc,
                                                    int* __restrict__ dtw_gt,
                                                    int* __restrict__ cc_fail2) {
    __shared__ __align__(16) float smem[SMEMF];
    const float INF = __builtin_inff();
    int u = blockIdx.x;
    int tid = threadIdx.x;
    int w = tid >> 6;
    int lane = tid & 63;

    if (u % 5 == 0) {
        // ------------------------------ DTW ------------------------------
        // Wave handles pairs p0=8j+2w, p0+1 (always same b: 20 is even).
        int j  = u / 5;                  // 0..319
        int p0 = j * 8 + w * 2;          // first pair of this wave
        int b  = p0 / K_;
        int k0 = p0 - b * K_;            // pair A k; pair B k = k0+1
        int b_lo = (j * 8) / K_;
        int b_hi = (j * 8 + 7) / K_;     // b_lo or b_lo+1
        float* tile0 = smem;
        float* tile1 = smem + TILEF;

        // Stage x[b_lo] -> tile0, x[b_hi] -> tile1 (all 256 threads, both).
        {
            int c  = tid >> 5;
            int t0 = (tid & 31) * 4;
            float4 v0 = *(const float4*)(x + ((size_t)b_lo * C_ + c) * T_ + t0);
            float4 v1 = *(const float4*)(x + ((size_t)b_hi * C_ + c) * T_ + t0);
            tile0[(t0 + 0) * 12 + c] = v0.x;
            tile0[(t0 + 1) * 12 + c] = v0.y;
            tile0[(t0 + 2) * 12 + c] = v0.z;
            tile0[(t0 + 3) * 12 + c] = v0.w;
            tile1[(t0 + 0) * 12 + c] = v1.x;
            tile1[(t0 + 1) * 12 + c] = v1.y;
            tile1[(t0 + 2) * 12 + c] = v1.z;
            tile1[(t0 + 3) * 12 + c] = v1.w;
        }
        __syncthreads();
        {   // X2[t] -> col 8 (threads 0-127: tile0; 128-255: tile1)
            float* tt = (tid < T_) ? tile0 : tile1;
            int t = tid & (T_ - 1);
            const float* rp = tt + t * 12;
            float4 xa = *(const float4*)rp;
            float4 xh = *(const float4*)(rp + 4);
            float s = xa.x * xa.x;
            s = fmaf(xa.y, xa.y, s); s = fmaf(xa.z, xa.z, s); s = fmaf(xa.w, xa.w, s);
            s = fmaf(xh.x, xh.x, s); s = fmaf(xh.y, xh.y, s); s = fmaf(xh.z, xh.z, s);
            s = fmaf(xh.w, xh.w, s);
            tt[t * 12 + 8] = s;
        }
        __syncthreads();

        const float* tile = (b == b_lo) ? tile0 : tile1;

        // Barycenter cols for BOTH pairs: -2*b and B2 in registers.
        float bvA0[8], bvA1[8], bvB0[8], bvB1[8], B2A0, B2A1, B2B0, B2B1;
        {
            const float4* bpA = (const float4*)(bary + ((size_t)k0 * S_ + 2 * lane) * C_);
            const float4* bpB = (const float4*)(bary + ((size_t)(k0 + 1) * S_ + 2 * lane) * C_);
            float4 qa0 = bpA[0], qa1 = bpA[1], qa2 = bpA[2], qa3 = bpA[3];
            float4 qb0 = bpB[0], qb1 = bpB[1], qb2 = bpB[2], qb3 = bpB[3];
            bvA0[0]=qa0.x; bvA0[1]=qa0.y; bvA0[2]=qa0.z; bvA0[3]=qa0.w;
            bvA0[4]=qa1.x; bvA0[5]=qa1.y; bvA0[6]=qa1.z; bvA0[7]=qa1.w;
            bvA1[0]=qa2.x; bvA1[1]=qa2.y; bvA1[2]=qa2.z; bvA1[3]=qa2.w;
            bvA1[4]=qa3.x; bvA1[5]=qa3.y; bvA1[6]=qa3.z; bvA1[7]=qa3.w;
            bvB0[0]=qb0.x; bvB0[1]=qb0.y; bvB0[2]=qb0.z; bvB0[3]=qb0.w;
            bvB0[4]=qb1.x; bvB0[5]=qb1.y; bvB0[6]=qb1.z; bvB0[7]=qb1.w;
            bvB1[0]=qb2.x; bvB1[1]=qb2.y; bvB1[2]=qb2.z; bvB1[3]=qb2.w;
            bvB1[4]=qb3.x; bvB1[5]=qb3.y; bvB1[6]=qb3.z; bvB1[7]=qb3.w;
            float sA0=0.f, sA1=0.f, sB0=0.f, sB1=0.f;
            #pragma unroll
            for (int ch = 0; ch < 8; ++ch) {
                sA0 = fmaf(bvA0[ch], bvA0[ch], sA0);
                sA1 = fmaf(bvA1[ch], bvA1[ch], sA1);
                sB0 = fmaf(bvB0[ch], bvB0[ch], sB0);
                sB1 = fmaf(bvB1[ch], bvB1[ch], sB1);
            }
            B2A0 = sA0; B2A1 = sA1; B2B0 = sB0; B2B1 = sB1;
            #pragma unroll
            for (int ch = 0; ch < 8; ++ch) {
                bvA0[ch] *= -2.f; bvA1[ch] *= -2.f;
                bvB0[ch] *= -2.f; bvB1[ch] *= -2.f;
            }
        }

        float nA0 = INF, nA1 = INF, nB0 = INF, nB1 = INF;
        float dfix = (lane == 0) ? 0.f : INF;      // virtual D[-1][-1]=0, row 0 only

        __builtin_amdgcn_s_setprio(1);
        float4 xa_n = *(const float4*)tile;
        float4 xh_n = *(const float4*)(tile + 4);
        float x2_n  = tile[8];

        #pragma unroll 2
        for (int t = 0; t < T_; ++t) {
            float4 xa = xa_n, xh = xh_n;
            float X2t = x2_n;
            const float* rpn = tile + ((t + 1) & (T_ - 1)) * 12;
            xa_n = *(const float4*)rpn;
            xh_n = *(const float4*)(rpn + 4);
            x2_n = rpn[8];

            float xv[8];
            xv[0]=xa.x; xv[1]=xa.y; xv[2]=xa.z; xv[3]=xa.w;
            xv[4]=xh.x; xv[5]=xh.y; xv[6]=xh.z; xv[7]=xh.w;
            float aA0 = X2t + B2A0, aA1 = X2t + B2A1;
            float aB0 = X2t + B2B0, aB1 = X2t + B2B1;
            #pragma unroll
            for (int ch = 0; ch < 8; ++ch) {
                aA0 = fmaf(bvA0[ch], xv[ch], aA0);
                aA1 = fmaf(bvA1[ch], xv[ch], aA1);
                aB0 = fmaf(bvB0[ch], xv[ch], aB0);
                aB1 = fmaf(bvB1[ch], xv[ch], aB1);
            }
            aA0 = fmaxf(aA0, 0.f); aA1 = fmaxf(aA1, 0.f);
            aB0 = fmaxf(aB0, 0.f); aB1 = fmaxf(aB1, 0.f);

            float diagA = dppf<0x138, 0xf>(INF, nA1);
            float diagB = dppf<0x138, 0xf>(INF, nB1);
            float mA0 = fminf(fminf(nA0, diagA), dfix);
            float mB0 = fminf(fminf(nB0, diagB), dfix);
            float mA1 = fminf(nA1, nA0);
            float mB1 = fminf(nB1, nB0);
            dfix = INF;
            float CA0 = aA0 + mA0, CA1 = aA1 + mA1;
            float CB0 = aB0 + mB0, CB1 = aB1 + mB1;
            float CA = fminf(CA1, CA0 + aA1);  float AA = aA0 + aA1;
            float CB = fminf(CB1, CB0 + aB1);  float AB = aB0 + aB1;

            // Two interleaved 64-lane min-plus scans (identity (INF,0) via dpp-old).
            float CiA, AiA, CiB, AiB;
            #define SCAN_STEP(CTRL, RMASK)                                          \
                CiA = dppf<CTRL, RMASK>(INF, CA); AiA = dppf<CTRL, RMASK>(0.f, AA); \
                CiB = dppf<CTRL, RMASK>(INF, CB); AiB = dppf<CTRL, RMASK>(0.f, AB); \
                CA = fminf(CA, CiA + AA); AA = AA + AiA;                            \
                CB = fminf(CB, CiB + AB); AB = AB + AiB;
            SCAN_STEP(0x111, 0xf)   // row_shr:1
            SCAN_STEP(0x112, 0xf)   // row_shr:2
            SCAN_STEP(0x114, 0xf)   // row_shr:4
            SCAN_STEP(0x118, 0xf)   // row_shr:8
            SCAN_STEP(0x142, 0xa)   // row_bcast15 -> rows 1,3
            SCAN_STEP(0x143, 0xc)   // row_bcast31 -> rows 2,3
            #undef SCAN_STEP

            float CpA = dppf<0x138, 0xf>(INF, CA);
            float CpB = dppf<0x138, 0xf>(INF, CB);
            nA0 = fminf(CA0, CpA + aA0);  nA1 = CA;
            nB0 = fminf(CB0, CpB + aB0);  nB1 = CB;
        }
        __builtin_amdgcn_s_setprio(0);

        if (lane == 63) {
            dtw_gt[p0]     = (logf(nA1) > top_dist[k0])     ? 1 : 0;
            dtw_gt[p0 + 1] = (logf(nB1) > top_dist[k0 + 1]) ? 1 : 0;
        }
    } else {
        // ------------------------------ CC -------------------------------
        int cb = u - u / 5 - 1;          // 0..1279
        int bh = cb / 5;                 // (b, half)
        int g5 = cb - bh * 5;
        int b  = bh >> 1;
        int h  = bh & 1;
        int kk = g5 * 4 + w;             // 0..19
        int cbase = h * 4;

        float* xp = smem;                         // 4 x XROW (+guard), swizzled
        float* bt = smem + BT_BASE + w * (4 * BTROW);

        const float* xsrc = x + ((size_t)b * C_ + cbase) * T_;
        #pragma unroll
        for (int c = 0; c < 4; ++c) {
            for (int jj = tid; jj < XROW; jj += 256) {
                int t = jj - (S_ - 1);
                float v = (t >= 0 && t < T_) ? xsrc[c * T_ + t] : 0.f;
                xp[c * XROW + SWZ(jj)] = v;
            }
        }
        #pragma unroll
        for (int r = 0; r < 2; ++r) {
            int s = r * 64 + lane;
            float4 q = *(const float4*)(bary + ((size_t)kk * S_ + s) * C_ + cbase);
            bt[0 * BTROW + s] = q.x;
            bt[1 * BTROW + s] = q.y;
            bt[2 * BTROW + s] = q.z;
            bt[3 * BTROW + s] = q.w;
        }
        __syncthreads();

        int cl = lane >> 4;
        int gl = lane & 15;
        int lag0 = gl << 4;              // 16 lags/lane
        const float* xr = xp + cl * XROW;
        const float* br = bt + cl * BTROW;

        float wdw[20];
        #pragma unroll
        for (int i = 0; i < 5; ++i) {
            float4 v = *(const float4*)&xr[SWZ(lag0 + i * 4)];
            wdw[i * 4 + 0] = v.x; wdw[i * 4 + 1] = v.y;
            wdw[i * 4 + 2] = v.z; wdw[i * 4 + 3] = v.w;
        }
        float acc[16];
        #pragma unroll
        for (int jj = 0; jj < 16; ++jj) acc[jj] = 0.f;

        #pragma unroll 8
        for (int s4 = 0; s4 < S_; s4 += 4) {
            float4 bq = *(const float4*)&br[s4];
            float bvals[4] = {bq.x, bq.y, bq.z, bq.w};
            #pragma unroll
            for (int uu = 0; uu < 4; ++uu) {
                #pragma unroll
                for (int jj = 0; jj < 16; ++jj)
                    acc[jj] = fmaf(wdw[uu + jj], bvals[uu], acc[jj]);
            }
            #pragma unroll
            for (int i = 0; i < 16; ++i) wdw[i] = wdw[i + 4];
            float4 v = *(const float4*)&xr[SWZ(lag0 + s4 + 20)];  // last iter: unused, in-bounds
            wdw[16] = v.x; wdw[17] = v.y; wdw[18] = v.z; wdw[19] = v.w;
        }

        if (gl == 15) acc[15] = -INF;    // lag 255 doesn't exist
        float m = acc[0];
        #pragma unroll
        for (int jj = 1; jj < 16; ++jj) m = fmaxf(m, acc[jj]);
        #pragma unroll
        for (int off = 8; off >= 1; off >>= 1)
            m = fmaxf(m, __shfl_xor(m, off));

        bool fail = false;
        if (gl == 0) fail = (m <= bottom_cc[kk * C_ + cbase + cl]);
        unsigned long long bal = __ballot(fail);
        if (lane == 0) cc_fail2[(b * K_ + kk) * 2 + h] = (bal != 0ULL) ? 1 : 0;
    }
}

__global__ void final_kernel(const int* __restrict__ preds,
                             const int* __restrict__ dtw_gt,
                             const int* __restrict__ cc_fail2,
                             int* __restrict__ out) {
    int b = threadIdx.x;
    if (b < B_) {
        int dtw_all = 1, cc_all = 1;
        #pragma unroll
        for (int k = 0; k < K_; ++k) {
            dtw_all &= dtw_gt[b * K_ + k];
            cc_all &= (cc_fail2[(b * K_ + k) * 2] | cc_fail2[(b * K_ + k) * 2 + 1]);
        }
        out[b] = (dtw_all | cc_all) ? K_ : preds[b];
    }
}

extern "C" void kernel_launch(void* const* d_in, const int* in_sizes, int n_in,
                              void* d_out, int out_size, void* d_ws, size_t ws_size,
                              hipStream_t stream) {
    const float* x         = (const float*)d_in[0];  // [B, C, T]
    const int*   preds     = (const int*)d_in[1];    // [B]
    const float* bary      = (const float*)d_in[2];  // [K, S, C]
    const float* top_dist  = (const float*)d_in[3];  // [K]
    const float* bottom_cc = (const float*)d_in[4];  // [K, C]
    int* out = (int*)d_out;                          // [B] int32

    int* dtw_gt   = (int*)d_ws;                // [B*K]
    int* cc_fail2 = dtw_gt + B_ * K_;          // [B*K*2]

    fused_kernel<<<1600, 256, 0, stream>>>(x, bary, top_dist, bottom_cc, dtw_gt, cc_fail2);
    final_kernel<<<1, 128, 0, stream>>>(preds, dtw_gt, cc_fail2, out);
}